// Round 2
// baseline (789.541 us; speedup 1.0000x reference)
//
#include <hip/hip_runtime.h>

// Problem constants (from reference)
#define B       4
#define N_CLS   1000
#define SEQ_LEN 77
#define CTX_DIM 512
#define VIS_DIM 512
#define HID     32
#define N_CTX_B 4
#define N_CTX_A 4

#define ROWS      (N_CLS * SEQ_LEN)   // 77000 rows (n*77 + s)
#define C4        (CTX_DIM / 4)       // 128 float4 per row
#define ROWS_PER_BLOCK 4
#define NBLK      (ROWS / ROWS_PER_BLOCK)   // 19250 (exact: 77000 = 4*19250)

typedef float f4 __attribute__((ext_vector_type(4)));

// ---------------------------------------------------------------------------
// Kernel 1: bias = relu(im @ w1 + b1) @ w2 + b2   -> ws (4*512 floats)
// Single block, 256 threads. Stage A split-K (2-way) to halve serial latency.
// ---------------------------------------------------------------------------
__global__ __launch_bounds__(256) void mlp_bias_kernel(
    const float* __restrict__ im,    // (4, 512)
    const float* __restrict__ w1,    // (512, 32)
    const float* __restrict__ b1,    // (32)
    const float* __restrict__ w2,    // (32, 512)
    const float* __restrict__ b2,    // (512)
    float* __restrict__ bias_out)    // (4, 512)
{
    __shared__ float s_part[2][B * HID];
    __shared__ float s_hid[B][HID];
    const int t = threadIdx.x;

    // Stage A: hidden = relu(im @ w1 + b1); 128 outputs, 2 threads each (split-K).
    {
        const int k   = t >> 7;        // 0/1: which K-half
        const int idx = t & 127;       // output index (b*32 + h)
        const int b   = idx >> 5;
        const int h   = idx & 31;
        const int v0  = k * (VIS_DIM / 2);
        float acc = 0.0f;
#pragma unroll 8
        for (int v = 0; v < VIS_DIM / 2; ++v)
            acc += im[b * VIS_DIM + v0 + v] * w1[(v0 + v) * HID + h]; // w1 coalesced in h
        s_part[k][idx] = acc;
    }
    __syncthreads();
    if (t < B * HID) {
        const float a = s_part[0][t] + s_part[1][t] + b1[t & 31];
        s_hid[t >> 5][t & 31] = fmaxf(a, 0.0f);
    }
    __syncthreads();

    // Stage B: bias = hidden @ w2 + b2; 2048 outputs, 8 per thread.
#pragma unroll
    for (int i = 0; i < 8; ++i) {
        const int o = t + i * 256;     // 0..2047
        const int b = o >> 9;          // /512
        const int c = o & 511;
        float acc = b2[c];
#pragma unroll
        for (int h = 0; h < HID; ++h)
            acc += s_hid[b][h] * w2[h * CTX_DIM + c];               // w2 coalesced in c
        bias_out[o] = acc;
    }
}

// ---------------------------------------------------------------------------
// Kernel 2: scatter/copy, all 4 batch values fused per row.
// Block = 256 threads = 2 half-blocks; half p handles b = p and b = p+2.
// Each block covers 4 consecutive rows: emb row loaded ONCE device-wide
// (L1 serves the intra-block repeat), written 4x.
// NT loads + NT stores: emb is read exactly once and out is never re-read,
// so neither stream should allocate/churn L2/L3.
// Branch (ctx_b / ctx_a / emb) is uniform across the block per row.
// ---------------------------------------------------------------------------
__global__ __launch_bounds__(256) void scatter_kernel(
    const f4*  __restrict__ emb,       // (1000*77, 128) as f4
    const f4*  __restrict__ ctxb,      // (4, 128) as f4
    const f4*  __restrict__ ctxa,      // (4, 128) as f4
    const int* __restrict__ name_lens, // (1000)
    const f4*  __restrict__ bias,      // (4, 128) as f4 (from ws)
    f4*        __restrict__ out)       // (4, 77000, 128) as f4
{
    const int c4   = threadIdx.x & (C4 - 1);
    const int p    = threadIdx.x >> 7;           // 0/1 -> b = p, p+2
    const int row0 = blockIdx.x * ROWS_PER_BLOCK;

    // n changes at most once within the block's 4 consecutive rows.
    int n = row0 / SEQ_LEN;                       // magic-mul div, once per block
    int s = row0 - n * SEQ_LEN;

#pragma unroll
    for (int r = 0; r < ROWS_PER_BLOCK; ++r) {
        const int row = row0 + r;

        f4 v0, v1;
        if ((unsigned)(s - 1) < (unsigned)N_CTX_B) {
            // positions 1..4: ctx_beforename[s-1] + bias[b]
            const f4 c   = ctxb[(s - 1) * C4 + c4];
            const f4 bs0 = bias[p * C4 + c4];         // tiny, L1/L2-resident
            const f4 bs1 = bias[(p + 2) * C4 + c4];
            v0 = c + bs0;
            v1 = c + bs1;
        } else {
            const int sa = 1 + N_CTX_B + name_lens[n];
            if ((unsigned)(s - sa) < (unsigned)N_CTX_A) {
                const f4 c   = ctxa[(s - sa) * C4 + c4];
                const f4 bs0 = bias[p * C4 + c4];
                const f4 bs1 = bias[(p + 2) * C4 + c4];
                v0 = c + bs0;
                v1 = c + bs1;
            } else {
                v0 = __builtin_nontemporal_load(&emb[(size_t)row * C4 + c4]);
                v1 = v0;
            }
        }
        __builtin_nontemporal_store(v0, &out[((size_t)(p)     * ROWS + row) * C4 + c4]);
        __builtin_nontemporal_store(v1, &out[((size_t)(p + 2) * ROWS + row) * C4 + c4]);

        if (++s == SEQ_LEN) { s = 0; ++n; }
    }
}

// ---------------------------------------------------------------------------
extern "C" void kernel_launch(void* const* d_in, const int* in_sizes, int n_in,
                              void* d_out, int out_size, void* d_ws, size_t ws_size,
                              hipStream_t stream)
{
    const float* im   = (const float*)d_in[0];  // (4, 512)
    const float* w1   = (const float*)d_in[1];  // (512, 32)
    const float* b1   = (const float*)d_in[2];  // (32)
    const float* w2   = (const float*)d_in[3];  // (32, 512)
    const float* b2   = (const float*)d_in[4];  // (512)
    const float* ctxb = (const float*)d_in[5];  // (4, 512)
    const float* ctxa = (const float*)d_in[6];  // (4, 512)
    const float* emb  = (const float*)d_in[7];  // (1000, 77, 512)
    const int*   nl   = (const int*)d_in[8];    // (1000)
    float* out  = (float*)d_out;
    float* bias = (float*)d_ws;                 // 4*512 floats = 8 KB scratch

    mlp_bias_kernel<<<1, 256, 0, stream>>>(im, w1, b1, w2, b2, bias);

    scatter_kernel<<<NBLK, 256, 0, stream>>>(
        (const f4*)emb, (const f4*)ctxb, (const f4*)ctxa,
        nl, (const f4*)bias, (f4*)out);
}